// Round 1
// baseline (25.851 us; speedup 1.0000x reference)
//
#include <hip/hip_runtime.h>
#include <math.h>

// PositionalEncoding: out = x * sqrt(512) + pe, pe interleaved sin/cos of
// positions[b,s] * div_term[i], div_term[i] = 10000^(-i/256), d_model = 512.
//
// Memory-bound elementwise op. Each thread handles one float4 (4 outputs =
// 2 sin/cos pairs). Trig via HW v_exp/v_sin/v_cos (revolutions + fract
// reduction) to stay off the slow precise-libm path.

#define D_MODEL 512
#define F4_PER_ROW (D_MODEL / 4)   // 128

__global__ __launch_bounds__(256) void pe_kernel(
    const float4* __restrict__ x,
    const int*    __restrict__ positions,
    float4*       __restrict__ out,
    int nf4)
{
    const float SQRT_D  = 22.627416997969522f;        // sqrt(512)
    const float C2      = -0.05190512364928082f;      // -log2(10000)/256
    const float INV2PI  = 0.15915494309189535f;       // 1/(2*pi)

    int stride = gridDim.x * blockDim.x;
    for (int idx = blockIdx.x * blockDim.x + threadIdx.x; idx < nf4; idx += stride) {
        int row = idx >> 7;          // (b*S + s)
        int j   = idx & (F4_PER_ROW - 1);

        float pf = (float)positions[row];
        float4 v = x[idx];

        // pair indices i0 = 2j, i1 = 2j+1 in [0, 256)
        float i0  = (float)(2 * j);
        float dt0 = __builtin_amdgcn_exp2f(i0 * C2);          // 10000^(-i0/256)
        float dt1 = __builtin_amdgcn_exp2f((i0 + 1.0f) * C2);

        // angle in revolutions, reduced to [0,1) for v_sin/v_cos
        float r0 = pf * dt0 * INV2PI; r0 -= floorf(r0);
        float r1 = pf * dt1 * INV2PI; r1 -= floorf(r1);

        float4 o;
        o.x = v.x * SQRT_D + __builtin_amdgcn_sinf(r0);
        o.y = v.y * SQRT_D + __builtin_amdgcn_cosf(r0);
        o.z = v.z * SQRT_D + __builtin_amdgcn_sinf(r1);
        o.w = v.w * SQRT_D + __builtin_amdgcn_cosf(r1);

        out[idx] = o;
    }
}

extern "C" void kernel_launch(void* const* d_in, const int* in_sizes, int n_in,
                              void* d_out, int out_size, void* d_ws, size_t ws_size,
                              hipStream_t stream) {
    const float* x       = (const float*)d_in[0];
    const int*   pos     = (const int*)d_in[1];
    float*       out     = (float*)d_out;

    int nf4 = out_size / 4;                 // 16,777,216 / 4 = 4,194,304
    int block = 256;
    int grid  = 2048;                       // grid-stride; 256 CUs * 8 blocks
    pe_kernel<<<grid, block, 0, stream>>>(
        (const float4*)x, pos, (float4*)out, nf4);
}

// Round 3
// 25.153 us; speedup vs baseline: 1.0277x; 1.0277x over previous
//
#include <hip/hip_runtime.h>
#include <math.h>

// PositionalEncoding: out = x * sqrt(512) + pe, pe interleaved sin/cos of
// positions[b,s] * div_term[i], div_term[i] = 10000^(-i/256), d_model = 512.
//
// Memory-bound elementwise op (~134 MB traffic, floor ~21.3 us @ 6.3 TB/s).
// One float4 per thread, exact grid (no grid-stride loop) so every wave
// issues its load immediately — latency hidden by TLP, not loop pipelining.
// Non-temporal hints: pure streaming, no reuse. Uses clang native vector
// (ext_vector_type) since the nontemporal builtins reject HIP_vector_type.
// Trig via HW v_exp/v_sin/v_cos (revolutions + fract reduction).

#define D_MODEL 512
#define F4_PER_ROW (D_MODEL / 4)   // 128

typedef float f32x4 __attribute__((ext_vector_type(4)));

__global__ __launch_bounds__(256) void pe_kernel(
    const f32x4* __restrict__ x,
    const int*   __restrict__ positions,
    f32x4*       __restrict__ out,
    int nf4)
{
    const float SQRT_D   = 22.627416997969522f;       // sqrt(512)
    const float C2       = -0.05190512364928082f;     // -log2(10000)/256
    const float INV2PI   = 0.15915494309189535f;      // 1/(2*pi)
    const float DT_RATIO = 0.9646616199111993f;       // 10000^(-1/256)

    int idx = blockIdx.x * blockDim.x + threadIdx.x;
    if (idx >= nf4) return;

    int row = idx >> 7;              // (b*S + s)
    int j   = idx & (F4_PER_ROW - 1);

    f32x4 v  = __builtin_nontemporal_load(&x[idx]);
    float pr = (float)positions[row] * INV2PI;        // position in 1/(2pi) units

    // pair indices i0 = 2j, i1 = 2j+1 in [0, 256)
    float dt0 = __builtin_amdgcn_exp2f((float)(2 * j) * C2);  // 10000^(-2j/256)
    float dt1 = dt0 * DT_RATIO;

    // angle in revolutions, reduced to [0,1) for v_sin/v_cos
    float r0 = pr * dt0; r0 -= floorf(r0);
    float r1 = pr * dt1; r1 -= floorf(r1);

    f32x4 o;
    o.x = v.x * SQRT_D + __builtin_amdgcn_sinf(r0);
    o.y = v.y * SQRT_D + __builtin_amdgcn_cosf(r0);
    o.z = v.z * SQRT_D + __builtin_amdgcn_sinf(r1);
    o.w = v.w * SQRT_D + __builtin_amdgcn_cosf(r1);

    __builtin_nontemporal_store(o, &out[idx]);
}

extern "C" void kernel_launch(void* const* d_in, const int* in_sizes, int n_in,
                              void* d_out, int out_size, void* d_ws, size_t ws_size,
                              hipStream_t stream) {
    const float* x   = (const float*)d_in[0];
    const int*   pos = (const int*)d_in[1];
    float*       out = (float*)d_out;

    int nf4   = out_size / 4;              // 16,777,216 / 4 = 4,194,304
    int block = 256;
    int grid  = (nf4 + block - 1) / block; // 16384 — exact, one f4/thread
    pe_kernel<<<grid, block, 0, stream>>>(
        (const f32x4*)x, pos, (f32x4*)out, nf4);
}